// Round 6
// baseline (100.043 us; speedup 1.0000x reference)
//
#include <hip/hip_runtime.h>
#include <math.h>

#define HW   128
#define BH   8           // band height (output rows per thread)
#define C_CH 256

struct R12 { float l0, l1; float4 a, b; float r0, r1; };  // cols col0-2 .. col0+9
struct R10 { float l;      float4 a, b; float r;      };  // cols col0-1 .. col0+8

__device__ __forceinline__ void sig_tanh(float s, float& fg, float& th) {
    float sc = fminf(15.f, fmaxf(-15.f, s));
    float t  = __expf(-sc);                                   // e^-s
    float t2 = t * t;                                         // e^-2s
    fg = __builtin_amdgcn_rcpf(1.f + t);                      // sigmoid
    th = fmaf(2.f, __builtin_amdgcn_rcpf(1.f + t2), -1.f);    // tanh = 2/(1+t2)-1
}

__device__ __forceinline__ float tanh_fast(float s) {
    float sc = fminf(15.f, fmaxf(-15.f, s));
    float t2 = __expf(-2.f * sc);
    return fmaf(2.f, __builtin_amdgcn_rcpf(1.f + t2), -1.f);
}

// 10-wide stencil-row accumulate from a 12-wide input row
__device__ __forceinline__ void facc(float w0, float w1, float w2,
                                     const R12& y, R10& s) {
    s.l   = fmaf(w0, y.l0,  fmaf(w1, y.l1,  fmaf(w2, y.a.x, s.l)));
    s.a.x = fmaf(w0, y.l1,  fmaf(w1, y.a.x, fmaf(w2, y.a.y, s.a.x)));
    s.a.y = fmaf(w0, y.a.x, fmaf(w1, y.a.y, fmaf(w2, y.a.z, s.a.y)));
    s.a.z = fmaf(w0, y.a.y, fmaf(w1, y.a.z, fmaf(w2, y.a.w, s.a.z)));
    s.a.w = fmaf(w0, y.a.z, fmaf(w1, y.a.w, fmaf(w2, y.b.x, s.a.w)));
    s.b.x = fmaf(w0, y.a.w, fmaf(w1, y.b.x, fmaf(w2, y.b.y, s.b.x)));
    s.b.y = fmaf(w0, y.b.x, fmaf(w1, y.b.y, fmaf(w2, y.b.z, s.b.y)));
    s.b.z = fmaf(w0, y.b.y, fmaf(w1, y.b.z, fmaf(w2, y.b.w, s.b.z)));
    s.b.w = fmaf(w0, y.b.z, fmaf(w1, y.b.w, fmaf(w2, y.r0,  s.b.w)));
    s.r   = fmaf(w0, y.b.w, fmaf(w1, y.r0,  fmaf(w2, y.r1,  s.r)));
}

// 8-wide stencil-row accumulate from a 10-wide input row
__device__ __forceinline__ void oacc(float w0, float w1, float w2,
                                     const R10& v, float4& s0, float4& s1) {
    s0.x = fmaf(w0, v.l,   fmaf(w1, v.a.x, fmaf(w2, v.a.y, s0.x)));
    s0.y = fmaf(w0, v.a.x, fmaf(w1, v.a.y, fmaf(w2, v.a.z, s0.y)));
    s0.z = fmaf(w0, v.a.y, fmaf(w1, v.a.z, fmaf(w2, v.a.w, s0.z)));
    s0.w = fmaf(w0, v.a.z, fmaf(w1, v.a.w, fmaf(w2, v.b.x, s0.w)));
    s1.x = fmaf(w0, v.a.w, fmaf(w1, v.b.x, fmaf(w2, v.b.y, s1.x)));
    s1.y = fmaf(w0, v.b.x, fmaf(w1, v.b.y, fmaf(w2, v.b.z, s1.y)));
    s1.z = fmaf(w0, v.b.y, fmaf(w1, v.b.z, fmaf(w2, v.b.w, s1.z)));
    s1.w = fmaf(w0, v.b.z, fmaf(w1, v.b.w, fmaf(w2, v.r,   s1.w)));
}

// No cross-lane ops, no LDS: halo columns are recomputed redundantly so each
// thread's 12-iteration unrolled loop is pure independent FMA/exp + global
// loads the compiler can pipeline. (256,4): cap 128 VGPR — body needs ~115.
__global__ __launch_bounds__(256, 4) void fused_gated_dwconv_nh(
    const float* __restrict__ x, const float* __restrict__ y,
    const float* __restrict__ w, const float* __restrict__ b,
    float* __restrict__ out)
{
    const int tid   = threadIdx.x;
    const int s     = tid & 15;          // col strip (8 cols each)
    const int band  = tid >> 4;          // 16 bands of 8 rows
    const int plane = blockIdx.x;
    const int c     = plane & (C_CH - 1);
    const int rb    = band * BH;
    const int col0  = s * 8;
    const bool sL = (s == 0), sR = (s == 15);

    const size_t poff = (size_t)plane * (HW * HW);
    const float* yp = y + poff;
    const float* xp = x + poff;
    float*       op = out + poff;

    float wk[9];
    #pragma unroll
    for (int k = 0; k < 9; ++k) wk[k] = w[c * 9 + k];
    const float bias = b[c];

    R12 yw[3];
    R10 xw[3];
    float4 fga[2], fgb[2];   // f_gate center 8 cols, 2-row rotation

    #pragma unroll
    for (int t = 0; t < BH + 4; ++t) {
        // ---- load y row rb-2+t (12 wide) into slot t%3 ----
        {
            int gy = rb - 2 + t;
            bool iny = (unsigned)gy < (unsigned)HW;
            const float* p = yp + (size_t)(iny ? gy : 0) * HW;
            float2 lv = *reinterpret_cast<const float2*>(p + (sL ? col0 : col0 - 2));
            float4 av = *reinterpret_cast<const float4*>(p + col0);
            float4 bv = *reinterpret_cast<const float4*>(p + col0 + 4);
            float2 rv = *reinterpret_cast<const float2*>(p + (sR ? col0 : col0 + 8));
            R12 Y;
            bool okL = iny && !sL, okR = iny && !sR;
            Y.l0 = okL ? lv.x : 0.f;
            Y.l1 = okL ? lv.y : 0.f;
            Y.a  = iny ? av : make_float4(0.f, 0.f, 0.f, 0.f);
            Y.b  = iny ? bv : make_float4(0.f, 0.f, 0.f, 0.f);
            Y.r0 = okR ? rv.x : 0.f;
            Y.r1 = okR ? rv.y : 0.f;
            yw[t % 3] = Y;
        }
        // ---- x_stage row q = rb-3+t (10 wide, halo recomputed) ----
        if (t >= 2) {
            int q = rb - 3 + t;
            bool inx = (unsigned)q < (unsigned)HW;
            const float* p = xp + (size_t)(inx ? q : 0) * HW;
            float  xl = *(p + (sL ? col0 : col0 - 1));
            float4 xa = *reinterpret_cast<const float4*>(p + col0);
            float4 xb = *reinterpret_cast<const float4*>(p + col0 + 4);
            float  xr = *(p + (sR ? col0 : col0 + 8));

            R10 F;
            F.l = bias; F.a = make_float4(bias, bias, bias, bias); F.b = F.a; F.r = bias;
            facc(wk[0], wk[1], wk[2], yw[(t - 2) % 3], F);
            facc(wk[3], wk[4], wk[5], yw[(t - 1) % 3], F);
            facc(wk[6], wk[7], wk[8], yw[t % 3],       F);

            float fgl, thl, fgr, thr;
            float4 fa, ta, fb, tb;
            sig_tanh(F.l,   fgl,  thl);
            sig_tanh(F.a.x, fa.x, ta.x);
            sig_tanh(F.a.y, fa.y, ta.y);
            sig_tanh(F.a.z, fa.z, ta.z);
            sig_tanh(F.a.w, fa.w, ta.w);
            sig_tanh(F.b.x, fb.x, tb.x);
            sig_tanh(F.b.y, fb.y, tb.y);
            sig_tanh(F.b.z, fb.z, tb.z);
            sig_tanh(F.b.w, fb.w, tb.w);
            sig_tanh(F.r,   fgr,  thr);

            R10 XS;
            XS.l   = (inx && !sL) ? fgl * (xl + thl) : 0.f;
            XS.a.x = fa.x * (xa.x + ta.x);
            XS.a.y = fa.y * (xa.y + ta.y);
            XS.a.z = fa.z * (xa.z + ta.z);
            XS.a.w = fa.w * (xa.w + ta.w);
            XS.b.x = fb.x * (xb.x + tb.x);
            XS.b.y = fb.y * (xb.y + tb.y);
            XS.b.z = fb.z * (xb.z + tb.z);
            XS.b.w = fb.w * (xb.w + tb.w);
            XS.r   = (inx && !sR) ? fgr * (xr + thr) : 0.f;
            if (!inx) {
                XS.a = make_float4(0.f, 0.f, 0.f, 0.f);
                XS.b = make_float4(0.f, 0.f, 0.f, 0.f);
            }
            xw[t % 3] = XS;
            fga[t & 1] = fa; fgb[t & 1] = fb;
        }
        // ---- output row r = rb-4+t ----
        if (t >= 4) {
            int r = rb - 4 + t;
            float4 s0 = make_float4(bias, bias, bias, bias), s1 = s0;
            oacc(wk[0], wk[1], wk[2], xw[(t - 2) % 3], s0, s1);
            oacc(wk[3], wk[4], wk[5], xw[(t - 1) % 3], s0, s1);
            oacc(wk[6], wk[7], wk[8], xw[t % 3],       s0, s1);

            const float4 fa = fga[(t + 1) & 1];
            const float4 fb = fgb[(t + 1) & 1];
            const R12&  Y  = yw[(t - 2) % 3];

            float4 o0, o1;
            o0.x = fmaf(tanh_fast(s0.x), fa.x, 2.f * Y.a.x);
            o0.y = fmaf(tanh_fast(s0.y), fa.y, 2.f * Y.a.y);
            o0.z = fmaf(tanh_fast(s0.z), fa.z, 2.f * Y.a.z);
            o0.w = fmaf(tanh_fast(s0.w), fa.w, 2.f * Y.a.w);
            o1.x = fmaf(tanh_fast(s1.x), fb.x, 2.f * Y.b.x);
            o1.y = fmaf(tanh_fast(s1.y), fb.y, 2.f * Y.b.y);
            o1.z = fmaf(tanh_fast(s1.z), fb.z, 2.f * Y.b.z);
            o1.w = fmaf(tanh_fast(s1.w), fb.w, 2.f * Y.b.w);

            float* po = op + (size_t)r * HW + col0;
            *reinterpret_cast<float4*>(po)     = o0;
            *reinterpret_cast<float4*>(po + 4) = o1;
        }
    }
}

extern "C" void kernel_launch(void* const* d_in, const int* in_sizes, int n_in,
                              void* d_out, int out_size, void* d_ws, size_t ws_size,
                              hipStream_t stream) {
    const float* x = (const float*)d_in[0];
    const float* y = (const float*)d_in[1];
    const float* w = (const float*)d_in[2];
    const float* b = (const float*)d_in[3];
    float* out = (float*)d_out;

    const int planes = in_sizes[0] / (HW * HW);   // B*C = 2048
    dim3 grid(planes);                            // 2048 blocks, 1 plane each
    dim3 block(256);
    fused_gated_dwconv_nh<<<grid, block, 0, stream>>>(x, y, w, b, out);
}